// Round 8
// baseline (3236.372 us; speedup 1.0000x reference)
//
#include <hip/hip_runtime.h>
#include <stdint.h>
#include <stddef.h>

#define BB 8
#define LL 1024
#define CC 512
#define KHn 4
#define HIDn 64
#define NLAYER 2
#define MM (BB*LL)

typedef __attribute__((ext_vector_type(4))) float f32x4;

// fp32 scratch strips inside the guaranteed-zero upper triangle of graphs L0:
// fp32 element f -> byte=4f; strip=byte>>11 (0..8191); matrix mk=strip>>9 (0..15),
// row=strip&511, bytes [2048,4096) of that row (cols 512..1023; all ref=0 there).
__device__ __forceinline__ float* strip_ptrf(char* base, size_t f){
  size_t byte = f << 2;
  size_t strip = byte >> 11;
  return (float*)(base + ((strip >> 9) << 22) + ((strip & 511) << 12) + 2048 + (byte & 2047));
}

// ---------------- BN fold ----------------
__global__ void k_scaleshift(const float* b1,const float* g1,const float* be1,const float* m1,const float* v1,
                             const float* b2,const float* g2,const float* be2,const float* m2,const float* v2,
                             float* sc1, float* sh1, float* sc2, float* sh2){
  int c = blockIdx.x*256 + threadIdx.x;
  if (c < CC){
    float s = g1[c]*rsqrtf(v1[c]+1e-5f); sc1[c]=s; sh1[c]=(b1[c]-m1[c])*s+be1[c];
  } else if (c < 2*CC){
    int d = c - CC;
    float s = g2[d]*rsqrtf(v2[d]+1e-5f); sc2[d]=s; sh2[d]=(b2[d]-m2[d])*s+be2[d];
  }
}

// ---------------- conv tower: O[l,o] = relu(BN(sum_{kk,i} w[o,i,kk] x[l+kk-2,i])) ----------------
__global__ __launch_bounds__(256,2)
void k_convg(const float* __restrict__ X, const float* __restrict__ W,
             const float* __restrict__ sc, const float* __restrict__ sh,
             float* __restrict__ O)
{
  __shared__ float As[32][33];
  __shared__ float Bs[32][33];
  const int tid = threadIdx.x, ty = tid >> 4, tx = tid & 15;
  const int m0 = blockIdx.x << 5, n0 = blockIdx.y << 5;
  float acc00=0.f, acc01=0.f, acc10=0.f, acc11=0.f;
  for (int seg = 0; seg < 3; ++seg){
    const int shift = seg - 2;
    for (int k0 = 0; k0 < CC; k0 += 32){
      __syncthreads();
      #pragma unroll
      for (int it = 0; it < 4; ++it){
        int idx = tid + (it << 8);
        int r = idx >> 5, c = idx & 31;
        int grow = m0 + r;
        float av = 0.f;
        if ((grow & (LL-1)) + shift >= 0) av = X[(size_t)(grow + shift)*CC + k0 + c];
        As[r][c] = av;
        Bs[r][c] = W[((size_t)(n0 + r)*CC + (k0 + c))*3 + seg];
      }
      __syncthreads();
      #pragma unroll
      for (int kk = 0; kk < 32; ++kk){
        float a0 = As[(ty<<1)][kk],   a1 = As[(ty<<1)+1][kk];
        float b0 = Bs[(tx<<1)][kk],   b1 = Bs[(tx<<1)+1][kk];
        acc00 += a0*b0; acc01 += a0*b1; acc10 += a1*b0; acc11 += a1*b1;
      }
    }
  }
  {
    int r0 = m0 + (ty<<1), c0 = n0 + (tx<<1);
    float s0 = sc[c0], s1 = sc[c0+1], h0 = sh[c0], h1 = sh[c0+1];
    O[(size_t)r0*CC + c0]       = fmaxf(acc00*s0 + h0, 0.f);
    O[(size_t)r0*CC + c0+1]     = fmaxf(acc01*s1 + h1, 0.f);
    O[(size_t)(r0+1)*CC + c0]   = fmaxf(acc10*s0 + h0, 0.f);
    O[(size_t)(r0+1)*CC + c0+1] = fmaxf(acc11*s1 + h1, 0.f);
  }
}

// ---------------- generic NT linear: C[m,n] = A[m,:]·B[n,:] + bias[n] ----------------
// SOUT=1: store via strip mapping into graphs-L0 zero triangle.
template<int SOUT>
__global__ __launch_bounds__(256,2)
void k_lin(const float* __restrict__ A, int lda,
           const float* __restrict__ B, int ldb, int K,
           const float* __restrict__ bias,
           float* __restrict__ O, int ldo, char* sbase)
{
  __shared__ float As[32][33];
  __shared__ float Bs[32][33];
  const int tid = threadIdx.x, ty = tid >> 4, tx = tid & 15;
  const int m0 = blockIdx.x << 5, n0 = blockIdx.y << 5;
  float acc00=0.f, acc01=0.f, acc10=0.f, acc11=0.f;
  for (int k0 = 0; k0 < K; k0 += 32){
    __syncthreads();
    #pragma unroll
    for (int it = 0; it < 4; ++it){
      int idx = tid + (it << 8);
      int r = idx >> 5, c = idx & 31;
      As[r][c] = A[(size_t)(m0 + r)*lda + k0 + c];
      Bs[r][c] = B[(size_t)(n0 + r)*ldb + k0 + c];
    }
    __syncthreads();
    #pragma unroll
    for (int kk = 0; kk < 32; ++kk){
      float a0 = As[(ty<<1)][kk],   a1 = As[(ty<<1)+1][kk];
      float b0 = Bs[(tx<<1)][kk],   b1 = Bs[(tx<<1)+1][kk];
      acc00 += a0*b0; acc01 += a0*b1; acc10 += a1*b0; acc11 += a1*b1;
    }
  }
  int r0 = m0 + (ty<<1), c0 = n0 + (tx<<1);
  float e0 = bias[c0], e1 = bias[c0+1];
  float v00 = acc00 + e0, v01 = acc01 + e1, v10 = acc10 + e0, v11 = acc11 + e1;
  if (SOUT){
    *strip_ptrf(sbase, (size_t)r0*ldo + c0)       = v00;
    *strip_ptrf(sbase, (size_t)r0*ldo + c0+1)     = v01;
    *strip_ptrf(sbase, (size_t)(r0+1)*ldo + c0)   = v10;
    *strip_ptrf(sbase, (size_t)(r0+1)*ldo + c0+1) = v11;
  } else {
    O[(size_t)r0*ldo + c0]       = v00;
    O[(size_t)r0*ldo + c0+1]     = v01;
    O[(size_t)(r0+1)*ldo + c0]   = v10;
    O[(size_t)(r0+1)*ldo + c0+1] = v11;
  }
}

// ---------------- scores: one wave per q-row; full-row write incl. zeros ----------------
__global__ __launch_bounds__(256,2)
void k_scoresf(const float* __restrict__ qv, const float* __restrict__ kv,
               float* __restrict__ gout)
{
  __shared__ float qrow[4][HIDn];
  const int tid = threadIdx.x, lane = tid & 63, w = tid >> 6;
  const int q0 = blockIdx.x << 2, kh = blockIdx.y, b = blockIdx.z;
  qrow[tid >> 6][tid & 63] =
      qv[((size_t)b*LL + q0 + (tid >> 6))*(KHn*HIDn) + kh*HIDn + (tid & 63)];
  __syncthreads();
  const int q = q0 + w;
  float* row = gout + ((size_t)(b*KHn + kh)*LL + q)*LL;
  const float* kb = kv + (size_t)b*LL*(KHn*HIDn) + kh*HIDn;
  float part = 0.f;
  for (int s = lane; s < LL; s += 64){
    float v = 0.f;
    if (s < q){
      const float4* kr = (const float4*)(kb + (size_t)s*(KHn*HIDn));
      float d = 0.f;
      #pragma unroll
      for (int h4 = 0; h4 < 16; ++h4){
        float4 k4 = kr[h4];
        d += qrow[w][h4*4+0]*k4.x + qrow[w][h4*4+1]*k4.y
           + qrow[w][h4*4+2]*k4.z + qrow[w][h4*4+3]*k4.w;
      }
      v = fmaxf(d, 0.f); v *= v; part += v;
    }
    row[s] = v;
  }
  part += __shfl_xor(part, 1);  part += __shfl_xor(part, 2);
  part += __shfl_xor(part, 4);  part += __shfl_xor(part, 8);
  part += __shfl_xor(part, 16); part += __shfl_xor(part, 32);
  float inv = 1.0f/(part + 1e-16f);
  for (int s = lane; s < q; s += 64) row[s] *= inv;
}

// ---------------- PV: outs[b,q,kh*128+n] = prev + sum_s att[q,s] val[s,n] ----------------
template<int VS>
__global__ __launch_bounds__(256,2)
void k_pvf(const float* __restrict__ att, const float* __restrict__ val, char* sbase,
           const float* __restrict__ prev, float* __restrict__ outs)
{
  __shared__ float As[32][33];
  __shared__ float Bs[32][33];
  const int tid = threadIdx.x, ty = tid >> 4, tx = tid & 15;
  const int m0 = blockIdx.x << 5, n0 = blockIdx.y << 5;
  const int b = blockIdx.z >> 2, kh = blockIdx.z & 3;
  const float* A = att + (size_t)(b*KHn + kh)*LL*LL;
  float acc00=0.f, acc01=0.f, acc10=0.f, acc11=0.f;
  for (int k0 = 0; k0 < LL; k0 += 32){
    __syncthreads();
    #pragma unroll
    for (int it = 0; it < 4; ++it){
      int idx = tid + (it << 8);
      int r = idx >> 5, c = idx & 31;
      As[r][c] = A[(size_t)(m0 + r)*LL + k0 + c];
      size_t f = ((size_t)b*LL + k0 + r)*CC + kh*128 + n0 + c;
      Bs[r][c] = VS ? *strip_ptrf(sbase, f) : val[f];
    }
    __syncthreads();
    #pragma unroll
    for (int kk = 0; kk < 32; ++kk){
      float a0 = As[(ty<<1)][kk],   a1 = As[(ty<<1)+1][kk];
      float b0 = Bs[kk][(tx<<1)],   b1 = Bs[kk][(tx<<1)+1];
      acc00 += a0*b0; acc01 += a0*b1; acc10 += a1*b0; acc11 += a1*b1;
    }
  }
  int row = m0 + (ty<<1);
  int col = kh*128 + n0 + (tx<<1);
  size_t o0 = ((size_t)b*LL + row)*CC + col;
  size_t o1 = ((size_t)b*LL + row + 1)*CC + col;
  outs[o0]   = prev[o0]   + acc00;
  outs[o0+1] = prev[o0+1] + acc01;
  outs[o1]   = prev[o1]   + acc10;
  outs[o1+1] = prev[o1+1] + acc11;
}

// restore borrowed strips (8192 x 2KB) to zero
__global__ void k_restore(char* gbase){
  size_t strip = blockIdx.x;
  char* p = gbase + ((strip >> 9) << 22) + ((strip & 511) << 12) + 2048;
  f32x4 z; z[0]=0.f; z[1]=0.f; z[2]=0.f; z[3]=0.f;
  ((f32x4*)p)[threadIdx.x] = z;
}

extern "C" void kernel_launch(void* const* d_in, const int* in_sizes, int n_in,
                              void* d_out, int out_size, void* d_ws, size_t ws_size,
                              hipStream_t stream)
{
  (void)in_sizes; (void)n_in; (void)out_size; (void)d_ws; (void)ws_size;  // d_ws unused
  const float* input  = (const float*)d_in[0];
  const float* ck_w   = (const float*)d_in[1];
  const float* ck_b   = (const float*)d_in[2];
  const float* ck_g   = (const float*)d_in[3];
  const float* ck_be  = (const float*)d_in[4];
  const float* ck_m   = (const float*)d_in[5];
  const float* ck_v   = (const float*)d_in[6];
  const float* cq_w   = (const float*)d_in[7];
  const float* cq_b   = (const float*)d_in[8];
  const float* cq_g   = (const float*)d_in[9];
  const float* cq_be  = (const float*)d_in[10];
  const float* cq_m   = (const float*)d_in[11];
  const float* cq_v   = (const float*)d_in[12];
  const float* qW     = (const float*)d_in[13];
  const float* qb     = (const float*)d_in[14];
  const float* kW     = (const float*)d_in[15];
  const float* kb     = (const float*)d_in[16];
  const float* vW     = (const float*)d_in[17];
  const float* vb     = (const float*)d_in[18];

  // d_out (fp32): graphs [2,8,4,1024,1024] = [0, 268.4MB); outs [2,8,1024,512] = [268.4, 302MB)
  float* graphs   = (float*)d_out;
  float* g1       = graphs + (size_t)BB*KHn*LL*LL;
  float* outsBase = graphs + (size_t)NLAYER*BB*KHn*LL*LL;
  float* outs0 = outsBase;
  float* outs1 = outsBase + (size_t)MM*CC;

  // scratch arena inside graphs L1 (fully overwritten by scores L1 at the end)
  char* RA = (char*)g1;
  float* key_out = (float*)(RA + 0);          // 16.78 MB
  float* qry_out = (float*)(RA + 16777216);   // 16.78 MB
  float* q0v     = (float*)(RA + 33554432);   // 8.39 MB
  float* k0v     = (float*)(RA + 41943040);   // 8.39 MB
  float* val0    = (float*)(RA + 50331648);   // 16.78 MB
  float* ck_sc   = (float*)(RA + 67108864);
  float* ck_sh   = (float*)(RA + 67110912);
  float* cq_sc   = (float*)(RA + 67112960);
  float* cq_sh   = (float*)(RA + 67115008);
  // layer-1 q/k in the outs-L1 region (dead before pv L1 writes it)
  float* q1v = outs1;                         // 8.39 MB
  float* k1v = outs1 + (size_t)MM*KHn*HIDn;   // 8.39 MB
  // layer-1 val lives in zero strips of graphs L0
  char* gL0 = (char*)d_out;

  k_scaleshift<<<4, 256, 0, stream>>>(ck_b, ck_g, ck_be, ck_m, ck_v,
                                      cq_b, cq_g, cq_be, cq_m, cq_v,
                                      ck_sc, ck_sh, cq_sc, cq_sh);
  k_convg<<<dim3(MM/32, CC/32), 256, 0, stream>>>(input, ck_w, ck_sc, ck_sh, key_out);
  k_convg<<<dim3(MM/32, CC/32), 256, 0, stream>>>(input, cq_w, cq_sc, cq_sh, qry_out);

  // ---- layer 0 ----
  k_lin<0><<<dim3(MM/32, (KHn*HIDn)/32), 256, 0, stream>>>(qry_out, CC, qW, CC, CC,
                                                           qb, q0v, KHn*HIDn, nullptr);
  k_lin<0><<<dim3(MM/32, (KHn*HIDn)/32), 256, 0, stream>>>(key_out, CC, kW, CC, CC,
                                                           kb, k0v, KHn*HIDn, nullptr);
  k_lin<0><<<dim3(MM/32, CC/32), 256, 0, stream>>>(input, CC, vW, CC, CC,
                                                   vb, val0, CC, nullptr);
  k_scoresf<<<dim3(LL/4, KHn, BB), 256, 0, stream>>>(q0v, k0v, graphs);
  k_pvf<0><<<dim3(LL/32, 4, BB*KHn), 256, 0, stream>>>(graphs, val0, nullptr, input, outs0);

  // ---- layer 1 ----
  k_lin<0><<<dim3(MM/32, (KHn*HIDn)/32), 256, 0, stream>>>(qry_out, CC,
                                                           qW + (size_t)KHn*HIDn*CC, CC, CC,
                                                           qb + KHn*HIDn, q1v, KHn*HIDn, nullptr);
  k_lin<0><<<dim3(MM/32, (KHn*HIDn)/32), 256, 0, stream>>>(key_out, CC,
                                                           kW + (size_t)KHn*HIDn*CC, CC, CC,
                                                           kb + KHn*HIDn, k1v, KHn*HIDn, nullptr);
  // val1 = outs0 @ vW1^T + vb1 -> zero strips of graphs L0 (pv L0 already consumed those zeros)
  k_lin<1><<<dim3(MM/32, CC/32), 256, 0, stream>>>(outs0, CC,
                                                   vW + (size_t)CC*CC, CC, CC,
                                                   vb + CC, nullptr, CC, gL0);
  // scores L1 destroys the arena (key/qry/q0/k0/val0/sc/sh all dead)
  k_scoresf<<<dim3(LL/4, KHn, BB), 256, 0, stream>>>(q1v, k1v, g1);
  // pv L1: outs1 = outs0 + att1 @ val1(strips); overwrites q1/k1 (dead)
  k_pvf<1><<<dim3(LL/32, 4, BB*KHn), 256, 0, stream>>>(g1, nullptr, gL0, outs0, outs1);
  // re-zero the borrowed strips
  k_restore<<<8192, 128, 0, stream>>>(gL0);
}